// Round 4
// baseline (379.395 us; speedup 1.0000x reference)
//
#include <hip/hip_runtime.h>
#include <hip/hip_bf16.h>

typedef __attribute__((ext_vector_type(8))) __bf16 bf16x8;
typedef __attribute__((ext_vector_type(4))) float f32x4;
typedef __attribute__((ext_vector_type(4))) unsigned int uint4v;

#define S_LEN 2048
#define DIM_  1024
#define HDIM  64
#define SCALE_F 0.03125f
#define QK_STR 80   // Qs/Ks row stride (160 B, 16B multiple)
#define V_STR  72   // Vt row stride (144 B, 16B multiple)
#define P_STR  80   // Ps row stride

__device__ __forceinline__ void async_copy16(const void* gp, void* lp) {
  __builtin_amdgcn_global_load_lds(
      (const __attribute__((address_space(1))) unsigned int*)gp,
      (__attribute__((address_space(3))) unsigned int*)lp, 16, 0, 0);
}

__device__ __forceinline__ unsigned short f2bf_u(float f) {
  unsigned u = __builtin_bit_cast(unsigned, f);
  u = (u + 0x7FFFu + ((u >> 16) & 1u)) >> 16;
  return (unsigned short)u;
}

// pack 8 f32 -> 8 bf16, single 16B LDS store
__device__ __forceinline__ void cvt8_store(void* dst, f32x4 a, f32x4 b) {
  uint4v o;
  o.x = (unsigned)f2bf_u(a[0]) | ((unsigned)f2bf_u(a[1]) << 16);
  o.y = (unsigned)f2bf_u(a[2]) | ((unsigned)f2bf_u(a[3]) << 16);
  o.z = (unsigned)f2bf_u(b[0]) | ((unsigned)f2bf_u(b[1]) << 16);
  o.w = (unsigned)f2bf_u(b[2]) | ((unsigned)f2bf_u(b[3]) << 16);
  *(uint4v*)dst = o;
}

// ---------------- QKV projection: f32 in, bf16 out ----------------
// Out[m,n] = sum_k X[m,k]*W[n,k] + bias[n];  M=4096, N=K=1024
__global__ __launch_bounds__(256) void qkv_gemm_kernel(
    const float* __restrict__ xq, const float* __restrict__ xk,
    const float* __restrict__ xv,
    const float* __restrict__ Wq, const float* __restrict__ bq,
    const float* __restrict__ Wk, const float* __restrict__ bk,
    const float* __restrict__ Wv, const float* __restrict__ bv,
    __hip_bfloat16* __restrict__ Q, __hip_bfloat16* __restrict__ Kk,
    __hip_bfloat16* __restrict__ V)
{
  const float *X, *W, *bias; __hip_bfloat16* Out;
  if (blockIdx.z == 0)      { X = xq; W = Wq; bias = bq; Out = Q;  }
  else if (blockIdx.z == 1) { X = xk; W = Wk; bias = bk; Out = Kk; }
  else                      { X = xv; W = Wv; bias = bv; Out = V;  }

  constexpr int K = 1024, N = 1024;
  __shared__ alignas(16) __hip_bfloat16 As[128 * 32];
  __shared__ alignas(16) __hip_bfloat16 Bs[128 * 32];
  const int tid  = threadIdx.x;
  const int lane = tid & 63;
  const int wave = tid >> 6;
  const int t    = lane & 15;
  const int quad = lane >> 4;
  const int wm   = wave >> 1;
  const int wn   = wave & 1;
  const int m0   = blockIdx.x * 128;
  const int n0   = blockIdx.y * 128;

  f32x4 acc[4][4] = {};

  for (int k0 = 0; k0 < K; k0 += 32) {
    // global loads first (overlap with previous iteration's MFMA)
    f32x4 xa[2][2], wb[2][2];
#pragma unroll
    for (int rr = 0; rr < 2; ++rr) {
      int c = rr * 256 + tid;
      int row = c >> 2, col = (c & 3) * 8;
      const float* gx = &X[(size_t)(m0 + row) * K + k0 + col];
      const float* gw = &W[(size_t)(n0 + row) * K + k0 + col];
      xa[rr][0] = *(const f32x4*)gx;  xa[rr][1] = *(const f32x4*)(gx + 4);
      wb[rr][0] = *(const f32x4*)gw;  wb[rr][1] = *(const f32x4*)(gw + 4);
    }
    __syncthreads();
#pragma unroll
    for (int rr = 0; rr < 2; ++rr) {
      int c = rr * 256 + tid;
      int row = c >> 2, col = (c & 3) * 8;
      cvt8_store(&As[row * 32 + col], xa[rr][0], xa[rr][1]);
      cvt8_store(&Bs[row * 32 + col], wb[rr][0], wb[rr][1]);
    }
    __syncthreads();
    bf16x8 a[4], b[4];
#pragma unroll
    for (int i = 0; i < 4; ++i)
      a[i] = *(const bf16x8*)&As[(wm * 64 + i * 16 + t) * 32 + quad * 8];
#pragma unroll
    for (int j = 0; j < 4; ++j)
      b[j] = *(const bf16x8*)&Bs[(wn * 64 + j * 16 + t) * 32 + quad * 8];
#pragma unroll
    for (int i = 0; i < 4; ++i)
#pragma unroll
      for (int j = 0; j < 4; ++j)
        acc[i][j] = __builtin_amdgcn_mfma_f32_16x16x32_bf16(a[i], b[j], acc[i][j], 0, 0, 0);
  }

  float bj[4];
#pragma unroll
  for (int j = 0; j < 4; ++j)
    bj[j] = bias[n0 + wn * 64 + j * 16 + t];
#pragma unroll
  for (int i = 0; i < 4; ++i)
#pragma unroll
    for (int j = 0; j < 4; ++j)
#pragma unroll
      for (int r = 0; r < 4; ++r) {
        int m = m0 + wm * 64 + i * 16 + quad * 4 + r;
        int n = n0 + wn * 64 + j * 16 + t;
        Out[(size_t)m * N + n] = __float2bfloat16(acc[i][j][r] + bj[j]);
      }
}

// ---------------- Output projection: bf16 A (async staging), f32 W, f32 out ----------------
__global__ __launch_bounds__(256) void proj_gemm_kernel(
    const __hip_bfloat16* __restrict__ X, const float* __restrict__ W,
    const float* __restrict__ bias, float* __restrict__ Out)
{
  constexpr int K = 1024, N = 1024;
  __shared__ alignas(16) __hip_bfloat16 As[128 * 32];
  __shared__ alignas(16) __hip_bfloat16 Bs[128 * 32];
  const int tid  = threadIdx.x;
  const int lane = tid & 63;
  const int wave = tid >> 6;
  const int t    = lane & 15;
  const int quad = lane >> 4;
  const int wm   = wave >> 1;
  const int wn   = wave & 1;
  const int m0   = blockIdx.x * 128;
  const int n0   = blockIdx.y * 128;

  f32x4 acc[4][4] = {};

  for (int k0 = 0; k0 < K; k0 += 32) {
    f32x4 wb[2][2];
#pragma unroll
    for (int rr = 0; rr < 2; ++rr) {
      int c = rr * 256 + tid;
      int row = c >> 2, col = (c & 3) * 8;
      const float* gw = &W[(size_t)(n0 + row) * K + k0 + col];
      wb[rr][0] = *(const f32x4*)gw;  wb[rr][1] = *(const f32x4*)(gw + 4);
    }
    __syncthreads();
#pragma unroll
    for (int rr = 0; rr < 2; ++rr) {
      int c = rr * 256 + tid;
      int row = c >> 2, col = (c & 3) * 8;
      async_copy16(&X[(size_t)(m0 + row) * K + k0 + col], &As[c * 8]);
      cvt8_store(&Bs[row * 32 + col], wb[rr][0], wb[rr][1]);
    }
    __syncthreads();
    bf16x8 a[4], b[4];
#pragma unroll
    for (int i = 0; i < 4; ++i)
      a[i] = *(const bf16x8*)&As[(wm * 64 + i * 16 + t) * 32 + quad * 8];
#pragma unroll
    for (int j = 0; j < 4; ++j)
      b[j] = *(const bf16x8*)&Bs[(wn * 64 + j * 16 + t) * 32 + quad * 8];
#pragma unroll
    for (int i = 0; i < 4; ++i)
#pragma unroll
      for (int j = 0; j < 4; ++j)
        acc[i][j] = __builtin_amdgcn_mfma_f32_16x16x32_bf16(a[i], b[j], acc[i][j], 0, 0, 0);
  }

  float bj[4];
#pragma unroll
  for (int j = 0; j < 4; ++j)
    bj[j] = bias[n0 + wn * 64 + j * 16 + t];
#pragma unroll
  for (int i = 0; i < 4; ++i)
#pragma unroll
    for (int j = 0; j < 4; ++j)
#pragma unroll
      for (int r = 0; r < 4; ++r) {
        int m = m0 + wm * 64 + i * 16 + quad * 4 + r;
        int n = n0 + wn * 64 + j * 16 + t;
        Out[(size_t)m * N + n] = acc[i][j][r] + bj[j];
      }
}

// ---------------- Flash attention (all-bf16 workspace; unchanged structure) ----------------
__global__ __launch_bounds__(256) void attn_kernel(
    const __hip_bfloat16* __restrict__ Qb,
    const __hip_bfloat16* __restrict__ Kb,
    const __hip_bfloat16* __restrict__ Vb,
    const int* __restrict__ mask,
    __hip_bfloat16* __restrict__ Ob)
{
  const int bid = blockIdx.x;
  const int qt = bid & 31;
  const int h  = (bid >> 5) & 15;
  const int b  = bid >> 9;
  const int qb = qt * 64;

  __shared__ alignas(16) __hip_bfloat16 Qs[64 * QK_STR];
  __shared__ alignas(16) __hip_bfloat16 Ks[64 * QK_STR];
  __shared__ alignas(16) __hip_bfloat16 Vt[64 * V_STR];   // Vt[dv][kv]
  __shared__ alignas(16) __hip_bfloat16 Ps[64 * P_STR];   // Ps[q][kv], wave-private rows

  const int tid  = threadIdx.x;
  const int lane = tid & 63;
  const int wave = tid >> 6;
  const int t    = lane & 15;
  const int quad = lane >> 4;

#pragma unroll
  for (int r = 0; r < 2; ++r) {
    int c = r * 256 + tid;
    int row = c >> 3, d0 = (c & 7) * 8;
    uint4 raw = *(const uint4*)&Qb[((size_t)(b * S_LEN + qb + row)) * DIM_ + h * HDIM + d0];
    *(uint4*)&Qs[row * QK_STR + d0] = raw;
  }
  __syncthreads();

  bf16x8 qf[2];
#pragma unroll
  for (int ks = 0; ks < 2; ++ks)
    qf[ks] = *(const bf16x8*)&Qs[(wave * 16 + t) * QK_STR + ks * 32 + quad * 8];

  float m_i = -3.0e38f;
  float l_i = 0.f;
  f32x4 o[4] = {};

  const int qg = qb + wave * 16 + t;
  const size_t mrow = ((size_t)b * S_LEN + qg) * S_LEN;

  for (int kvt = 0; kvt < 32; ++kvt) {
    const int kvb = kvt * 64;
    __syncthreads();
#pragma unroll
    for (int r = 0; r < 2; ++r) {
      int c = r * 256 + tid;
      int row = c >> 3, d0 = (c & 7) * 8;
      uint4 kraw = *(const uint4*)&Kb[((size_t)(b * S_LEN + kvb + row)) * DIM_ + h * HDIM + d0];
      *(uint4*)&Ks[row * QK_STR + d0] = kraw;
      uint4 vraw = *(const uint4*)&Vb[((size_t)(b * S_LEN + kvb + row)) * DIM_ + h * HDIM + d0];
      const __hip_bfloat16* ve = (const __hip_bfloat16*)&vraw;
#pragma unroll
      for (int u = 0; u < 8; ++u)
        Vt[(d0 + u) * V_STR + row] = ve[u];
    }
    __syncthreads();

    // St[kv][q] = K·Q^T  (verified 16x16x32 operand pattern)
    f32x4 s4[4];
#pragma unroll
    for (int i = 0; i < 4; ++i) {
      f32x4 z = {};
      bf16x8 a0 = *(const bf16x8*)&Ks[(i * 16 + t) * QK_STR + quad * 8];
      z = __builtin_amdgcn_mfma_f32_16x16x32_bf16(a0, qf[0], z, 0, 0, 0);
      bf16x8 a1 = *(const bf16x8*)&Ks[(i * 16 + t) * QK_STR + 32 + quad * 8];
      z = __builtin_amdgcn_mfma_f32_16x16x32_bf16(a1, qf[1], z, 0, 0, 0);
      s4[i] = z;
    }

    float p[4][4];
    float mx = -3.0e38f;
#pragma unroll
    for (int i = 0; i < 4; ++i) {
      int4 mk = *(const int4*)&mask[mrow + kvb + i * 16 + quad * 4];
      const int* mp = &mk.x;
#pragma unroll
      for (int r = 0; r < 4; ++r) {
        float v = mp[r] ? -1e20f : s4[i][r] * SCALE_F;
        p[i][r] = v;
        mx = fmaxf(mx, v);
      }
    }
    mx = fmaxf(mx, __shfl_xor(mx, 16, 64));
    mx = fmaxf(mx, __shfl_xor(mx, 32, 64));
    float m_new = fmaxf(m_i, mx);
    float alpha = __expf(m_i - m_new);
    float sum = 0.f;
#pragma unroll
    for (int i = 0; i < 4; ++i)
#pragma unroll
      for (int r = 0; r < 4; ++r) {
        float e = __expf(p[i][r] - m_new);
        p[i][r] = e;
        sum += e;
      }
    sum += __shfl_xor(sum, 16, 64);
    sum += __shfl_xor(sum, 32, 64);
    l_i = alpha * l_i + sum;
    m_i = m_new;

    float alr[4];
#pragma unroll
    for (int r = 0; r < 4; ++r)
      alr[r] = __shfl(alpha, quad * 4 + r, 64);
#pragma unroll
    for (int n = 0; n < 4; ++n)
#pragma unroll
      for (int r = 0; r < 4; ++r)
        o[n][r] *= alr[r];

    // P -> LDS (wave-private rows), then PV with verified operand pattern
#pragma unroll
    for (int i = 0; i < 4; ++i)
#pragma unroll
      for (int r = 0; r < 4; ++r)
        Ps[(wave * 16 + t) * P_STR + i * 16 + quad * 4 + r] = __float2bfloat16(p[i][r]);

#pragma unroll
    for (int ks = 0; ks < 2; ++ks) {
      bf16x8 pa = *(const bf16x8*)&Ps[(wave * 16 + t) * P_STR + ks * 32 + quad * 8];
#pragma unroll
      for (int n = 0; n < 4; ++n) {
        bf16x8 vb = *(const bf16x8*)&Vt[(n * 16 + t) * V_STR + ks * 32 + quad * 8];
        o[n] = __builtin_amdgcn_mfma_f32_16x16x32_bf16(pa, vb, o[n], 0, 0, 0);
      }
    }
  }

  float lr[4];
#pragma unroll
  for (int r = 0; r < 4; ++r)
    lr[r] = __shfl(l_i, quad * 4 + r, 64);
#pragma unroll
  for (int n = 0; n < 4; ++n)
#pragma unroll
    for (int r = 0; r < 4; ++r) {
      int q2 = qb + wave * 16 + quad * 4 + r;
      int col = h * HDIM + n * 16 + t;
      Ob[((size_t)b * S_LEN + q2) * DIM_ + col] = __float2bfloat16(o[n][r] / lr[r]);
    }
}

extern "C" void kernel_launch(void* const* d_in, const int* in_sizes, int n_in,
                              void* d_out, int out_size, void* d_ws, size_t ws_size,
                              hipStream_t stream) {
  const float* q  = (const float*)d_in[0];
  const float* k  = (const float*)d_in[1];
  const float* v  = (const float*)d_in[2];
  const int*   mk = (const int*)d_in[3];
  const float* Wq = (const float*)d_in[4];
  const float* bq = (const float*)d_in[5];
  const float* Wk = (const float*)d_in[6];
  const float* bk = (const float*)d_in[7];
  const float* Wv = (const float*)d_in[8];
  const float* bv = (const float*)d_in[9];
  const float* Wo = (const float*)d_in[10];
  const float* bo = (const float*)d_in[11];
  float* out = (float*)d_out;

  const size_t TOK = (size_t)2 * 2048 * 1024;   // 4M bf16 elements per buffer
  __hip_bfloat16* Qb = (__hip_bfloat16*)d_ws;
  __hip_bfloat16* Kb = Qb + TOK;
  __hip_bfloat16* Vb = Kb + TOK;
  __hip_bfloat16* Ob = Vb + TOK;

  qkv_gemm_kernel<<<dim3(32, 8, 3), 256, 0, stream>>>(q, k, v, Wq, bq, Wk, bk, Wv, bv, Qb, Kb, Vb);
  attn_kernel<<<dim3(1024), 256, 0, stream>>>(Qb, Kb, Vb, mk, Ob);
  proj_gemm_kernel<<<dim3(32, 8), 256, 0, stream>>>(Ob, Wo, bo, out);
}

// Round 6
// 322.114 us; speedup vs baseline: 1.1778x; 1.1778x over previous
//
#include <hip/hip_runtime.h>
#include <hip/hip_bf16.h>

typedef __attribute__((ext_vector_type(8))) __bf16 bf16x8;
typedef __attribute__((ext_vector_type(4))) float f32x4;
typedef __attribute__((ext_vector_type(4))) unsigned int uint4v;
typedef __attribute__((ext_vector_type(2))) unsigned int uint2v;

#define S_LEN 2048
#define DIM_  1024
#define HDIM  64
// SCALE / ln2 folded for exp2-domain softmax: 0.03125 * log2(e)
#define SCALE2 0.045084441f
#define QK_STR 80   // Qs/Ks row stride (160 B)
#define V_STR  72   // Vt row stride (144 B = 9*16, b128-aligned rows)
#define P_STR  80   // Ps row stride

#define EXP2F(x) __builtin_amdgcn_exp2f(x)

__device__ __forceinline__ void async_copy16(const void* gp, void* lp) {
  __builtin_amdgcn_global_load_lds(
      (const __attribute__((address_space(1))) unsigned int*)gp,
      (__attribute__((address_space(3))) unsigned int*)lp, 16, 0, 0);
}

__device__ __forceinline__ unsigned f2bf_u(float f) {
  unsigned u = __builtin_bit_cast(unsigned, f);
  return (u + 0x7FFFu + ((u >> 16) & 1u)) >> 16;
}
__device__ __forceinline__ unsigned pack2(float a, float b) {
  return f2bf_u(a) | (f2bf_u(b) << 16);
}

// ---------------- input f32 -> bf16 conversion (7 regions, one launch) ----------------
__global__ __launch_bounds__(256) void cvt_kernel(
    const float* __restrict__ s0, const float* __restrict__ s1, const float* __restrict__ s2,
    const float* __restrict__ s3, const float* __restrict__ s4, const float* __restrict__ s5,
    const float* __restrict__ s6,
    __hip_bfloat16* __restrict__ d0, __hip_bfloat16* __restrict__ d1, __hip_bfloat16* __restrict__ d2,
    __hip_bfloat16* __restrict__ d3, __hip_bfloat16* __restrict__ d4, __hip_bfloat16* __restrict__ d5,
    __hip_bfloat16* __restrict__ d6)
{
  const float* srcs[7] = {s0, s1, s2, s3, s4, s5, s6};
  __hip_bfloat16* dsts[7] = {d0, d1, d2, d3, d4, d5, d6};
  const int sizes[7] = {4194304, 4194304, 4194304, 1048576, 1048576, 1048576, 1048576};
  int rg = blockIdx.y;
  int base = (blockIdx.x * 256 + threadIdx.x) * 8;
  if (base >= sizes[rg]) return;
  const float* s = srcs[rg] + base;
  f32x4 a = *(const f32x4*)s;
  f32x4 b = *(const f32x4*)(s + 4);
  uint4v o;
  o.x = pack2(a[0], a[1]); o.y = pack2(a[2], a[3]);
  o.z = pack2(b[0], b[1]); o.w = pack2(b[2], b[3]);
  *(uint4v*)(dsts[rg] + base) = o;
}

// ---------------- mask int32 -> 64-bit words via ballot ----------------
// bits[(b*2048+q)*32 + kvt] bit j = mask[b][q][kvt*64+j]
__global__ __launch_bounds__(256) void maskbits_kernel(
    const int* __restrict__ mask, unsigned long long* __restrict__ bits)
{
  int w = (blockIdx.x * 256 + threadIdx.x) >> 6;   // global wave id, 131072 total
  int lane = threadIdx.x & 63;
  int m = mask[(size_t)w * 64 + lane];
  unsigned long long bal = __ballot(m != 0);
  if (lane == 0) bits[w] = bal;
}

// ---------------- QKV projection (all-bf16, verified async staging) ----------------
// Out[m,n] = sum_k X[m,k]*W[n,k] + bias[n]; z==2 writes V^T [b,h,dv,kv]
__global__ __launch_bounds__(256) void qkv_gemm_kernel(
    const __hip_bfloat16* __restrict__ xq, const __hip_bfloat16* __restrict__ xk,
    const __hip_bfloat16* __restrict__ xv,
    const __hip_bfloat16* __restrict__ Wq, const float* __restrict__ bq,
    const __hip_bfloat16* __restrict__ Wk, const float* __restrict__ bk,
    const __hip_bfloat16* __restrict__ Wv, const float* __restrict__ bv,
    __hip_bfloat16* __restrict__ Q, __hip_bfloat16* __restrict__ Kk,
    __hip_bfloat16* __restrict__ VT)
{
  const __hip_bfloat16 *X, *W; const float* bias;
  if (blockIdx.z == 0)      { X = xq; W = Wq; bias = bq; }
  else if (blockIdx.z == 1) { X = xk; W = Wk; bias = bk; }
  else                      { X = xv; W = Wv; bias = bv; }

  constexpr int K = 1024, N = 1024;
  __shared__ alignas(16) __hip_bfloat16 As[128 * 32];
  __shared__ alignas(16) __hip_bfloat16 Bs[128 * 32];
  const int tid  = threadIdx.x;
  const int lane = tid & 63;
  const int wave = tid >> 6;
  const int t    = lane & 15;
  const int quad = lane >> 4;
  const int wm   = wave >> 1;
  const int wn   = wave & 1;
  const int m0   = blockIdx.x * 128;
  const int n0   = blockIdx.y * 128;

  f32x4 acc[4][4] = {};

  for (int k0 = 0; k0 < K; k0 += 32) {
    __syncthreads();
#pragma unroll
    for (int r = 0; r < 2; ++r) {
      int c   = r * 256 + tid;
      int row = c >> 2;
      int col = (c & 3) * 8;
      async_copy16(&X[(size_t)(m0 + row) * K + k0 + col], &As[c * 8]);
      async_copy16(&W[(size_t)(n0 + row) * K + k0 + col], &Bs[c * 8]);
    }
    __syncthreads();
    bf16x8 a[4], b[4];
#pragma unroll
    for (int i = 0; i < 4; ++i)
      a[i] = *(const bf16x8*)&As[(wm * 64 + i * 16 + t) * 32 + quad * 8];
#pragma unroll
    for (int j = 0; j < 4; ++j)
      b[j] = *(const bf16x8*)&Bs[(wn * 64 + j * 16 + t) * 32 + quad * 8];
#pragma unroll
    for (int i = 0; i < 4; ++i)
#pragma unroll
      for (int j = 0; j < 4; ++j)
        acc[i][j] = __builtin_amdgcn_mfma_f32_16x16x32_bf16(a[i], b[j], acc[i][j], 0, 0, 0);
  }

  float bj[4];
#pragma unroll
  for (int j = 0; j < 4; ++j)
    bj[j] = bias[n0 + wn * 64 + j * 16 + t];

  if (blockIdx.z == 2) {
    // V^T epilogue: VT[((b*16+h)*64+dv)*2048 + kv], 4 consecutive kv per lane
#pragma unroll
    for (int i = 0; i < 4; ++i)
#pragma unroll
      for (int j = 0; j < 4; ++j) {
        int m = m0 + wm * 64 + i * 16 + quad * 4;      // kv base (r=0)
        int n = n0 + wn * 64 + j * 16 + t;
        int bb = m >> 11, kv = m & 2047;
        int hh = n >> 6,  dv = n & 63;
        uint2v o;
        o.x = pack2(acc[i][j][0] + bj[j], acc[i][j][1] + bj[j]);
        o.y = pack2(acc[i][j][2] + bj[j], acc[i][j][3] + bj[j]);
        *(uint2v*)&VT[(size_t)(((bb * 16 + hh) * 64) + dv) * 2048 + kv] = o;
      }
  } else {
    __hip_bfloat16* Out = (blockIdx.z == 0) ? Q : Kk;
#pragma unroll
    for (int i = 0; i < 4; ++i)
#pragma unroll
      for (int j = 0; j < 4; ++j)
#pragma unroll
        for (int r = 0; r < 4; ++r) {
          int m = m0 + wm * 64 + i * 16 + quad * 4 + r;
          int n = n0 + wn * 64 + j * 16 + t;
          Out[(size_t)m * N + n] = __float2bfloat16(acc[i][j][r] + bj[j]);
        }
  }
}

// ---------------- Output projection: bf16 A/B async staging, f32 out ----------------
__global__ __launch_bounds__(256) void proj_gemm_kernel(
    const __hip_bfloat16* __restrict__ X, const __hip_bfloat16* __restrict__ W,
    const float* __restrict__ bias, float* __restrict__ Out)
{
  constexpr int K = 1024, N = 1024;
  __shared__ alignas(16) __hip_bfloat16 As[128 * 32];
  __shared__ alignas(16) __hip_bfloat16 Bs[128 * 32];
  const int tid  = threadIdx.x;
  const int lane = tid & 63;
  const int wave = tid >> 6;
  const int t    = lane & 15;
  const int quad = lane >> 4;
  const int wm   = wave >> 1;
  const int wn   = wave & 1;
  const int m0   = blockIdx.x * 128;
  const int n0   = blockIdx.y * 128;

  f32x4 acc[4][4] = {};

  for (int k0 = 0; k0 < K; k0 += 32) {
    __syncthreads();
#pragma unroll
    for (int r = 0; r < 2; ++r) {
      int c   = r * 256 + tid;
      int row = c >> 2;
      int col = (c & 3) * 8;
      async_copy16(&X[(size_t)(m0 + row) * K + k0 + col], &As[c * 8]);
      async_copy16(&W[(size_t)(n0 + row) * K + k0 + col], &Bs[c * 8]);
    }
    __syncthreads();
    bf16x8 a[4], b[4];
#pragma unroll
    for (int i = 0; i < 4; ++i)
      a[i] = *(const bf16x8*)&As[(wm * 64 + i * 16 + t) * 32 + quad * 8];
#pragma unroll
    for (int j = 0; j < 4; ++j)
      b[j] = *(const bf16x8*)&Bs[(wn * 64 + j * 16 + t) * 32 + quad * 8];
#pragma unroll
    for (int i = 0; i < 4; ++i)
#pragma unroll
      for (int j = 0; j < 4; ++j)
        acc[i][j] = __builtin_amdgcn_mfma_f32_16x16x32_bf16(a[i], b[j], acc[i][j], 0, 0, 0);
  }

  float bj[4];
#pragma unroll
  for (int j = 0; j < 4; ++j)
    bj[j] = bias[n0 + wn * 64 + j * 16 + t];
#pragma unroll
  for (int i = 0; i < 4; ++i)
#pragma unroll
    for (int j = 0; j < 4; ++j)
#pragma unroll
      for (int r = 0; r < 4; ++r) {
        int m = m0 + wm * 64 + i * 16 + quad * 4 + r;
        int n = n0 + wn * 64 + j * 16 + t;
        Out[(size_t)m * N + n] = acc[i][j][r] + bj[j];
      }
}

// ---------------- Flash attention ----------------
__global__ __launch_bounds__(256) void attn_kernel(
    const __hip_bfloat16* __restrict__ Qb,
    const __hip_bfloat16* __restrict__ Kb,
    const __hip_bfloat16* __restrict__ VT,
    const unsigned long long* __restrict__ mbits,
    __hip_bfloat16* __restrict__ Ob)
{
  const int bid = blockIdx.x;
  const int qt = bid & 31;
  const int h  = (bid >> 5) & 15;
  const int b  = bid >> 9;
  const int qb = qt * 64;

  __shared__ alignas(16) __hip_bfloat16 Qs[64 * QK_STR];
  __shared__ alignas(16) __hip_bfloat16 Ks[64 * QK_STR];
  __shared__ alignas(16) __hip_bfloat16 Vt[64 * V_STR];   // Vt[dv][kv]
  __shared__ alignas(16) __hip_bfloat16 Ps[64 * P_STR];   // Ps[q][kv], wave-private rows

  const int tid  = threadIdx.x;
  const int lane = tid & 63;
  const int wave = tid >> 6;
  const int t    = lane & 15;
  const int quad = lane >> 4;

#pragma unroll
  for (int r = 0; r < 2; ++r) {
    int c = r * 256 + tid;
    int row = c >> 3, d0 = (c & 7) * 8;
    uint4 raw = *(const uint4*)&Qb[((size_t)(b * S_LEN + qb + row)) * DIM_ + h * HDIM + d0];
    *(uint4*)&Qs[row * QK_STR + d0] = raw;
  }
  __syncthreads();

  bf16x8 qf[2];
#pragma unroll
  for (int ks = 0; ks < 2; ++ks)
    qf[ks] = *(const bf16x8*)&Qs[(wave * 16 + t) * QK_STR + ks * 32 + quad * 8];

  float m_i = -3.0e38f;
  float l_i = 0.f;
  f32x4 o[4] = {};

  const int qg = qb + wave * 16 + t;
  const size_t vtbase = (size_t)((b * 16 + h) * 64) * 2048;
  const size_t mbase = ((size_t)b * S_LEN + qg) * 32;

  for (int kvt = 0; kvt < 32; ++kvt) {
    const int kvb = kvt * 64;
    unsigned long long mw = mbits[mbase + kvt];
    __syncthreads();
#pragma unroll
    for (int r = 0; r < 2; ++r) {
      int c = r * 256 + tid;
      int row = c >> 3, d0 = (c & 7) * 8;
      uint4 kraw = *(const uint4*)&Kb[((size_t)(b * S_LEN + kvb + row)) * DIM_ + h * HDIM + d0];
      *(uint4*)&Ks[row * QK_STR + d0] = kraw;
      uint4 vraw = *(const uint4*)&VT[vtbase + (size_t)row * 2048 + kvb + d0];
      *(uint4*)&Vt[row * V_STR + d0] = vraw;   // Vt[dv][kv]
    }
    __syncthreads();

    // St[kv][q] = K·Q^T  (verified 16x16x32 operand pattern)
    f32x4 s4[4];
#pragma unroll
    for (int i = 0; i < 4; ++i) {
      f32x4 z = {};
      bf16x8 a0 = *(const bf16x8*)&Ks[(i * 16 + t) * QK_STR + quad * 8];
      z = __builtin_amdgcn_mfma_f32_16x16x32_bf16(a0, qf[0], z, 0, 0, 0);
      bf16x8 a1 = *(const bf16x8*)&Ks[(i * 16 + t) * QK_STR + 32 + quad * 8];
      z = __builtin_amdgcn_mfma_f32_16x16x32_bf16(a1, qf[1], z, 0, 0, 0);
      s4[i] = z;
    }

    // mask + scale in exp2 domain; lane holds St[kv=i*16+quad*4+r][q=t]
    float p[4][4];
    float mx = -3.0e38f;
#pragma unroll
    for (int i = 0; i < 4; ++i) {
      unsigned mq = (unsigned)((mw >> (i * 16 + quad * 4)) & 0xFull);
#pragma unroll
      for (int r = 0; r < 4; ++r) {
        float v = ((mq >> r) & 1u) ? -1e20f : s4[i][r] * SCALE2;
        p[i][r] = v;
        mx = fmaxf(mx, v);
      }
    }
    mx = fmaxf(mx, __shfl_xor(mx, 16, 64));
    mx = fmaxf(mx, __shfl_xor(mx, 32, 64));
    float m_new = fmaxf(m_i, mx);
    float alpha = EXP2F(m_i - m_new);
    float sum = 0.f;
#pragma unroll
    for (int i = 0; i < 4; ++i)
#pragma unroll
      for (int r = 0; r < 4; ++r) {
        float e = EXP2F(p[i][r] - m_new);
        p[i][r] = e;
        sum += e;
      }
    sum += __shfl_xor(sum, 16, 64);
    sum += __shfl_xor(sum, 32, 64);
    l_i = alpha * l_i + sum;
    m_i = m_new;

    float alr[4];
#pragma unroll
    for (int r = 0; r < 4; ++r)
      alr[r] = __shfl(alpha, quad * 4 + r, 64);
#pragma unroll
    for (int n = 0; n < 4; ++n)
#pragma unroll
      for (int r = 0; r < 4; ++r)
        o[n][r] *= alr[r];

    // P -> LDS, packed b64 stores (wave-private rows, conflict-free)
#pragma unroll
    for (int i = 0; i < 4; ++i) {
      uint2v pk;
      pk.x = pack2(p[i][0], p[i][1]);
      pk.y = pack2(p[i][2], p[i][3]);
      *(uint2v*)&Ps[(wave * 16 + t) * P_STR + i * 16 + quad * 4] = pk;
    }

#pragma unroll
    for (int ks = 0; ks < 2; ++ks) {
      bf16x8 pa = *(const bf16x8*)&Ps[(wave * 16 + t) * P_STR + ks * 32 + quad * 8];
#pragma unroll
      for (int n = 0; n < 4; ++n) {
        bf16x8 vb = *(const bf16x8*)&Vt[(n * 16 + t) * V_STR + ks * 32 + quad * 8];
        o[n] = __builtin_amdgcn_mfma_f32_16x16x32_bf16(pa, vb, o[n], 0, 0, 0);
      }
    }
  }

  float lr[4];
#pragma unroll
  for (int r = 0; r < 4; ++r)
    lr[r] = __shfl(l_i, quad * 4 + r, 64);
#pragma unroll
  for (int n = 0; n < 4; ++n)
#pragma unroll
    for (int r = 0; r < 4; ++r) {
      int q2 = qb + wave * 16 + quad * 4 + r;
      int col = h * HDIM + n * 16 + t;
      Ob[((size_t)b * S_LEN + q2) * DIM_ + col] = __float2bfloat16(o[n][r] / lr[r]);
    }
}

extern "C" void kernel_launch(void* const* d_in, const int* in_sizes, int n_in,
                              void* d_out, int out_size, void* d_ws, size_t ws_size,
                              hipStream_t stream) {
  const float* q  = (const float*)d_in[0];
  const float* k  = (const float*)d_in[1];
  const float* v  = (const float*)d_in[2];
  const int*   mk = (const int*)d_in[3];
  const float* Wq = (const float*)d_in[4];
  const float* bq = (const float*)d_in[5];
  const float* Wk = (const float*)d_in[6];
  const float* bk = (const float*)d_in[7];
  const float* Wv = (const float*)d_in[8];
  const float* bv = (const float*)d_in[9];
  const float* Wo = (const float*)d_in[10];
  const float* bo = (const float*)d_in[11];
  float* out = (float*)d_out;

  char* ws = (char*)d_ws;
  const size_t MB = 1024 * 1024;
  __hip_bfloat16* Qb  = (__hip_bfloat16*)(ws);            //  8 MB
  __hip_bfloat16* Kb  = (__hip_bfloat16*)(ws + 8  * MB);  //  8 MB
  __hip_bfloat16* VTb = (__hip_bfloat16*)(ws + 16 * MB);  //  8 MB
  __hip_bfloat16* Ob  = (__hip_bfloat16*)(ws + 24 * MB);  //  8 MB
  __hip_bfloat16* xqb = (__hip_bfloat16*)(ws + 32 * MB);  //  8 MB
  __hip_bfloat16* xkb = (__hip_bfloat16*)(ws + 40 * MB);  //  8 MB
  __hip_bfloat16* xvb = (__hip_bfloat16*)(ws + 48 * MB);  //  8 MB
  __hip_bfloat16* Wqb = (__hip_bfloat16*)(ws + 56 * MB);  //  2 MB
  __hip_bfloat16* Wkb = (__hip_bfloat16*)(ws + 58 * MB);  //  2 MB
  __hip_bfloat16* Wvb = (__hip_bfloat16*)(ws + 60 * MB);  //  2 MB
  __hip_bfloat16* Wob = (__hip_bfloat16*)(ws + 62 * MB);  //  2 MB
  unsigned long long* mbits = (unsigned long long*)(ws + 64 * MB); // 1 MB

  cvt_kernel<<<dim3(2048, 7), 256, 0, stream>>>(q, k, v, Wq, Wk, Wv, Wo,
                                                xqb, xkb, xvb, Wqb, Wkb, Wvb, Wob);
  maskbits_kernel<<<dim3(32768), 256, 0, stream>>>(mk, mbits);
  qkv_gemm_kernel<<<dim3(32, 8, 3), 256, 0, stream>>>(xqb, xkb, xvb,
                                                      Wqb, bq, Wkb, bk, Wvb, bv,
                                                      Qb, Kb, VTb);
  attn_kernel<<<dim3(1024), 256, 0, stream>>>(Qb, Kb, VTb, mbits, Ob);
  proj_gemm_kernel<<<dim3(32, 8), 256, 0, stream>>>(Ob, Wob, bo, out);
}

// Round 7
// 303.893 us; speedup vs baseline: 1.2484x; 1.0600x over previous
//
#include <hip/hip_runtime.h>
#include <hip/hip_bf16.h>

typedef __attribute__((ext_vector_type(8))) __bf16 bf16x8;
typedef __attribute__((ext_vector_type(4))) short short4v;
typedef __attribute__((ext_vector_type(4))) float f32x4;
typedef __attribute__((ext_vector_type(4))) unsigned int uint4v;
typedef __attribute__((ext_vector_type(2))) unsigned int uint2v;

#define S_LEN 2048
#define DIM_  1024
#define HDIM  64
// SCALE * log2(e), folded into Q at projection time
#define SCALE2 0.045084441f
#define QK_STR 80   // Qs/Ks row stride (160 B)
#define V_STR  72   // Vt row stride (144 B)

#define EXP2F(x) __builtin_amdgcn_exp2f(x)

__device__ __forceinline__ void async_copy16(const void* gp, void* lp) {
  __builtin_amdgcn_global_load_lds(
      (const __attribute__((address_space(1))) unsigned int*)gp,
      (__attribute__((address_space(3))) unsigned int*)lp, 16, 0, 0);
}

__device__ __forceinline__ unsigned f2bf_u(float f) {
  unsigned u = __builtin_bit_cast(unsigned, f);
  return (u + 0x7FFFu + ((u >> 16) & 1u)) >> 16;
}
__device__ __forceinline__ unsigned pack2(float a, float b) {
  return f2bf_u(a) | (f2bf_u(b) << 16);
}

// ---------------- input f32 -> bf16 conversion ----------------
__global__ __launch_bounds__(256) void cvt_kernel(
    const float* __restrict__ s0, const float* __restrict__ s1, const float* __restrict__ s2,
    const float* __restrict__ s3, const float* __restrict__ s4, const float* __restrict__ s5,
    const float* __restrict__ s6,
    __hip_bfloat16* __restrict__ d0, __hip_bfloat16* __restrict__ d1, __hip_bfloat16* __restrict__ d2,
    __hip_bfloat16* __restrict__ d3, __hip_bfloat16* __restrict__ d4, __hip_bfloat16* __restrict__ d5,
    __hip_bfloat16* __restrict__ d6)
{
  const float* srcs[7] = {s0, s1, s2, s3, s4, s5, s6};
  __hip_bfloat16* dsts[7] = {d0, d1, d2, d3, d4, d5, d6};
  const int sizes[7] = {4194304, 4194304, 4194304, 1048576, 1048576, 1048576, 1048576};
  int rg = blockIdx.y;
  int base = (blockIdx.x * 256 + threadIdx.x) * 8;
  if (base >= sizes[rg]) return;
  const float* s = srcs[rg] + base;
  f32x4 a = *(const f32x4*)s;
  f32x4 b = *(const f32x4*)(s + 4);
  uint4v o;
  o.x = pack2(a[0], a[1]); o.y = pack2(a[2], a[3]);
  o.z = pack2(b[0], b[1]); o.w = pack2(b[2], b[3]);
  *(uint4v*)(dsts[rg] + base) = o;
}

// ---------------- mask int32 -> 64-bit words via ballot ----------------
__global__ __launch_bounds__(256) void maskbits_kernel(
    const int* __restrict__ mask, unsigned long long* __restrict__ bits)
{
  int w = (blockIdx.x * 256 + threadIdx.x) >> 6;
  int lane = threadIdx.x & 63;
  int m = mask[(size_t)w * 64 + lane];
  unsigned long long bal = __ballot(m != 0);
  if (lane == 0) bits[w] = bal;
}

// L2 swizzle: 8 consecutive blocks (-> 8 XCDs) share one n-tile, sweep m.
__device__ __forceinline__ void swz(int r, int& m0, int& n0) {
  int g  = r >> 6;          // 0..3
  int yy = (r >> 3) & 7;    // n tile
  int xl = r & 7;           // m sub
  m0 = (g * 8 + xl) * 128;
  n0 = yy * 128;
}

// ---------------- QKV projection (bf16, async staging) ----------------
// z==0 writes Q pre-scaled by SCALE2; z==2 writes V^T [b,h,dv,kv]
__global__ __launch_bounds__(256) void qkv_gemm_kernel(
    const __hip_bfloat16* __restrict__ xq, const __hip_bfloat16* __restrict__ xk,
    const __hip_bfloat16* __restrict__ xv,
    const __hip_bfloat16* __restrict__ Wq, const float* __restrict__ bq,
    const __hip_bfloat16* __restrict__ Wk, const float* __restrict__ bk,
    const __hip_bfloat16* __restrict__ Wv, const float* __restrict__ bv,
    __hip_bfloat16* __restrict__ Q, __hip_bfloat16* __restrict__ Kk,
    __hip_bfloat16* __restrict__ VT)
{
  const __hip_bfloat16 *X, *W; const float* bias;
  if (blockIdx.z == 0)      { X = xq; W = Wq; bias = bq; }
  else if (blockIdx.z == 1) { X = xk; W = Wk; bias = bk; }
  else                      { X = xv; W = Wv; bias = bv; }

  constexpr int K = 1024, N = 1024;
  __shared__ alignas(16) __hip_bfloat16 As[128 * 32];
  __shared__ alignas(16) __hip_bfloat16 Bs[128 * 32];
  const int tid  = threadIdx.x;
  const int lane = tid & 63;
  const int wave = tid >> 6;
  const int t    = lane & 15;
  const int quad = lane >> 4;
  const int wm   = wave >> 1;
  const int wn   = wave & 1;
  int m0, n0;
  swz(blockIdx.x, m0, n0);

  f32x4 acc[4][4] = {};

  for (int k0 = 0; k0 < K; k0 += 32) {
    __syncthreads();
#pragma unroll
    for (int r = 0; r < 2; ++r) {
      int c   = r * 256 + tid;
      int row = c >> 2;
      int col = (c & 3) * 8;
      async_copy16(&X[(size_t)(m0 + row) * K + k0 + col], &As[c * 8]);
      async_copy16(&W[(size_t)(n0 + row) * K + k0 + col], &Bs[c * 8]);
    }
    __syncthreads();
    bf16x8 a[4], b[4];
#pragma unroll
    for (int i = 0; i < 4; ++i)
      a[i] = *(const bf16x8*)&As[(wm * 64 + i * 16 + t) * 32 + quad * 8];
#pragma unroll
    for (int j = 0; j < 4; ++j)
      b[j] = *(const bf16x8*)&Bs[(wn * 64 + j * 16 + t) * 32 + quad * 8];
#pragma unroll
    for (int i = 0; i < 4; ++i)
#pragma unroll
      for (int j = 0; j < 4; ++j)
        acc[i][j] = __builtin_amdgcn_mfma_f32_16x16x32_bf16(a[i], b[j], acc[i][j], 0, 0, 0);
  }

  float bj[4];
#pragma unroll
  for (int j = 0; j < 4; ++j)
    bj[j] = bias[n0 + wn * 64 + j * 16 + t];

  if (blockIdx.z == 2) {
#pragma unroll
    for (int i = 0; i < 4; ++i)
#pragma unroll
      for (int j = 0; j < 4; ++j) {
        int m = m0 + wm * 64 + i * 16 + quad * 4;
        int n = n0 + wn * 64 + j * 16 + t;
        int bb = m >> 11, kv = m & 2047;
        int hh = n >> 6,  dv = n & 63;
        uint2v o;
        o.x = pack2(acc[i][j][0] + bj[j], acc[i][j][1] + bj[j]);
        o.y = pack2(acc[i][j][2] + bj[j], acc[i][j][3] + bj[j]);
        *(uint2v*)&VT[(size_t)(((bb * 16 + hh) * 64) + dv) * 2048 + kv] = o;
      }
  } else {
    const bool isq = (blockIdx.z == 0);
    __hip_bfloat16* Out = isq ? Q : Kk;
    const float sc = isq ? SCALE2 : 1.0f;
#pragma unroll
    for (int i = 0; i < 4; ++i)
#pragma unroll
      for (int j = 0; j < 4; ++j)
#pragma unroll
        for (int r = 0; r < 4; ++r) {
          int m = m0 + wm * 64 + i * 16 + quad * 4 + r;
          int n = n0 + wn * 64 + j * 16 + t;
          Out[(size_t)m * N + n] = __float2bfloat16((acc[i][j][r] + bj[j]) * sc);
        }
  }
}

// ---------------- Output projection ----------------
__global__ __launch_bounds__(256) void proj_gemm_kernel(
    const __hip_bfloat16* __restrict__ X, const __hip_bfloat16* __restrict__ W,
    const float* __restrict__ bias, float* __restrict__ Out)
{
  constexpr int K = 1024, N = 1024;
  __shared__ alignas(16) __hip_bfloat16 As[128 * 32];
  __shared__ alignas(16) __hip_bfloat16 Bs[128 * 32];
  const int tid  = threadIdx.x;
  const int lane = tid & 63;
  const int wave = tid >> 6;
  const int t    = lane & 15;
  const int quad = lane >> 4;
  const int wm   = wave >> 1;
  const int wn   = wave & 1;
  int m0, n0;
  swz(blockIdx.x, m0, n0);

  f32x4 acc[4][4] = {};

  for (int k0 = 0; k0 < K; k0 += 32) {
    __syncthreads();
#pragma unroll
    for (int r = 0; r < 2; ++r) {
      int c   = r * 256 + tid;
      int row = c >> 2;
      int col = (c & 3) * 8;
      async_copy16(&X[(size_t)(m0 + row) * K + k0 + col], &As[c * 8]);
      async_copy16(&W[(size_t)(n0 + row) * K + k0 + col], &Bs[c * 8]);
    }
    __syncthreads();
    bf16x8 a[4], b[4];
#pragma unroll
    for (int i = 0; i < 4; ++i)
      a[i] = *(const bf16x8*)&As[(wm * 64 + i * 16 + t) * 32 + quad * 8];
#pragma unroll
    for (int j = 0; j < 4; ++j)
      b[j] = *(const bf16x8*)&Bs[(wn * 64 + j * 16 + t) * 32 + quad * 8];
#pragma unroll
    for (int i = 0; i < 4; ++i)
#pragma unroll
      for (int j = 0; j < 4; ++j)
        acc[i][j] = __builtin_amdgcn_mfma_f32_16x16x32_bf16(a[i], b[j], acc[i][j], 0, 0, 0);
  }

  float bj[4];
#pragma unroll
  for (int j = 0; j < 4; ++j)
    bj[j] = bias[n0 + wn * 64 + j * 16 + t];
#pragma unroll
  for (int i = 0; i < 4; ++i)
#pragma unroll
    for (int j = 0; j < 4; ++j)
#pragma unroll
      for (int r = 0; r < 4; ++r) {
        int m = m0 + wm * 64 + i * 16 + quad * 4 + r;
        int n = n0 + wn * 64 + j * 16 + t;
        Out[(size_t)m * N + n] = acc[i][j][r] + bj[j];
      }
}

// ---------------- Flash attention: O^T = V^T * P^T, register-resident P ----------------
__global__ __launch_bounds__(256) void attn_kernel(
    const __hip_bfloat16* __restrict__ Qb,
    const __hip_bfloat16* __restrict__ Kb,
    const __hip_bfloat16* __restrict__ VT,
    const unsigned long long* __restrict__ mbits,
    __hip_bfloat16* __restrict__ Ob)
{
  const int bid = blockIdx.x;
  const int qt = bid & 31;
  const int h  = (bid >> 5) & 15;
  const int b  = bid >> 9;
  const int qb = qt * 64;

  __shared__ alignas(16) __hip_bfloat16 Qs[64 * QK_STR];
  __shared__ alignas(16) __hip_bfloat16 Ks[64 * QK_STR];
  __shared__ alignas(16) __hip_bfloat16 Vt[64 * V_STR];   // Vt[dv][kv]

  const int tid  = threadIdx.x;
  const int lane = tid & 63;
  const int wave = tid >> 6;
  const int t    = lane & 15;
  const int quad = lane >> 4;

#pragma unroll
  for (int r = 0; r < 2; ++r) {
    int c = r * 256 + tid;
    int row = c >> 3, d0 = (c & 7) * 8;
    uint4 raw = *(const uint4*)&Qb[((size_t)(b * S_LEN + qb + row)) * DIM_ + h * HDIM + d0];
    *(uint4*)&Qs[row * QK_STR + d0] = raw;
  }
  __syncthreads();

  bf16x8 qf[2];
#pragma unroll
  for (int ks = 0; ks < 2; ++ks)
    qf[ks] = *(const bf16x8*)&Qs[(wave * 16 + t) * QK_STR + ks * 32 + quad * 8];

  float m_i = -3.0e38f;
  float l_i = 0.f;
  f32x4 o[4] = {};   // O^T[dv = n*16+quad*4+r][q = t]

  const int qg = qb + wave * 16 + t;              // stats q row (lane axis)
  const size_t vtbase = (size_t)((b * 16 + h) * 64) * 2048;
  const size_t mbase = ((size_t)b * S_LEN + qg) * 32;

  for (int kvt = 0; kvt < 32; ++kvt) {
    const int kvb = kvt * 64;
    unsigned long long mw = mbits[mbase + kvt];
    __syncthreads();
#pragma unroll
    for (int r = 0; r < 2; ++r) {
      int c = r * 256 + tid;
      int row = c >> 3, d0 = (c & 7) * 8;
      uint4 kraw = *(const uint4*)&Kb[((size_t)(b * S_LEN + kvb + row)) * DIM_ + h * HDIM + d0];
      *(uint4*)&Ks[row * QK_STR + d0] = kraw;
      uint4 vraw = *(const uint4*)&VT[vtbase + (size_t)row * 2048 + kvb + d0];
      *(uint4*)&Vt[row * V_STR + d0] = vraw;
    }
    __syncthreads();

    // St[kv][q] = K·(Q*SCALE2)^T
    f32x4 s4[4];
#pragma unroll
    for (int i = 0; i < 4; ++i) {
      f32x4 z = {};
      bf16x8 a0 = *(const bf16x8*)&Ks[(i * 16 + t) * QK_STR + quad * 8];
      z = __builtin_amdgcn_mfma_f32_16x16x32_bf16(a0, qf[0], z, 0, 0, 0);
      bf16x8 a1 = *(const bf16x8*)&Ks[(i * 16 + t) * QK_STR + 32 + quad * 8];
      z = __builtin_amdgcn_mfma_f32_16x16x32_bf16(a1, qf[1], z, 0, 0, 0);
      s4[i] = z;
    }

    // mask; lane holds St[kv=i*16+quad*4+r][q=t] (already scaled)
    float p[4][4];
    float mx = -3.0e38f;
#pragma unroll
    for (int i = 0; i < 4; ++i) {
      unsigned mq = (unsigned)((mw >> (i * 16 + quad * 4)) & 0xFull);
#pragma unroll
      for (int r = 0; r < 4; ++r) {
        float v = ((mq >> r) & 1u) ? -1e20f : s4[i][r];
        p[i][r] = v;
        mx = fmaxf(mx, v);
      }
    }
    mx = fmaxf(mx, __shfl_xor(mx, 16, 64));
    mx = fmaxf(mx, __shfl_xor(mx, 32, 64));
    float m_new = fmaxf(m_i, mx);
    float alpha = EXP2F(m_i - m_new);
    float sum = 0.f;
#pragma unroll
    for (int i = 0; i < 4; ++i)
#pragma unroll
      for (int r = 0; r < 4; ++r) {
        float e = EXP2F(p[i][r] - m_new);
        p[i][r] = e;
        sum += e;
      }
    sum += __shfl_xor(sum, 16, 64);
    sum += __shfl_xor(sum, 32, 64);
    l_i = alpha * l_i + sum;
    m_i = m_new;

    // rescale O^T: q = t = own lane -> no shuffle
#pragma unroll
    for (int n = 0; n < 4; ++n)
#pragma unroll
      for (int r = 0; r < 4; ++r)
        o[n][r] *= alpha;

    // pack P^T sub-tiles: B-frag of 16x16x16 (k=quad*4+i, n=t) == St C-layout
    short4v pf[4];
#pragma unroll
    for (int j = 0; j < 4; ++j) {
      uint2v pk;
      pk.x = pack2(p[j][0], p[j][1]);
      pk.y = pack2(p[j][2], p[j][3]);
      pf[j] = __builtin_bit_cast(short4v, pk);
    }

    // O^T += V^T · P^T  (A = V^T rows: A[m=t][k=quad*4+i])
#pragma unroll
    for (int j = 0; j < 4; ++j)
#pragma unroll
      for (int n = 0; n < 4; ++n) {
        short4v va = *(const short4v*)&Vt[(n * 16 + t) * V_STR + j * 16 + quad * 4];
        o[n] = __builtin_amdgcn_mfma_f32_16x16x16bf16_1k(va, pf[j], o[n], 0, 0, 0);
      }
  }

  // epilogue: normalize by own-lane l_i, transpose via LDS (reuse Qs), coalesced store
  float rl = 1.0f / l_i;
  __hip_bfloat16* Ts = Qs;   // [q 64][dv 64] stride V_STR
  __syncthreads();
#pragma unroll
  for (int n = 0; n < 4; ++n) {
    uint2v pk;
    pk.x = pack2(o[n][0] * rl, o[n][1] * rl);
    pk.y = pack2(o[n][2] * rl, o[n][3] * rl);
    *(uint2v*)&Ts[(wave * 16 + t) * V_STR + n * 16 + quad * 4] = pk;
  }
  __syncthreads();
  {
    int row = tid >> 2;          // q local
    int d0  = (tid & 3) * 16;    // dv base
    uint4 x0 = *(const uint4*)&Ts[row * V_STR + d0];
    uint4 x1 = *(const uint4*)&Ts[row * V_STR + d0 + 8];
    __hip_bfloat16* dst = &Ob[((size_t)(b * S_LEN + qb + row)) * DIM_ + h * HDIM + d0];
    *(uint4*)dst = x0;
    *(uint4*)(dst + 8) = x1;
  }
}

extern "C" void kernel_launch(void* const* d_in, const int* in_sizes, int n_in,
                              void* d_out, int out_size, void* d_ws, size_t ws_size,
                              hipStream_t stream) {
  const float* q  = (const float*)d_in[0];
  const float* k  = (const float*)d_in[1];
  const float* v  = (const float*)d_in[2];
  const int*   mk = (const int*)d_in[3];
  const float* Wq = (const float*)d_in[4];
  const float* bq = (const float*)d_in[5];
  const float* Wk = (const float*)d_in[6];
  const float* bk = (const float*)d_in[7];
  const float* Wv = (const float*)d_in[8];
  const float* bv = (const float*)d_in[9];
  const float* Wo = (const float*)d_in[10];
  const float* bo = (const float*)d_in[11];
  float* out = (float*)d_out;

  char* ws = (char*)d_ws;
  const size_t MB = 1024 * 1024;
  __hip_bfloat16* Qb  = (__hip_bfloat16*)(ws);
  __hip_bfloat16* Kb  = (__hip_bfloat16*)(ws + 8  * MB);
  __hip_bfloat16* VTb = (__hip_bfloat16*)(ws + 16 * MB);
  __hip_bfloat16* Ob  = (__hip_bfloat16*)(ws + 24 * MB);
  __hip_bfloat16* xqb = (__hip_bfloat16*)(ws + 32 * MB);
  __hip_bfloat16* xkb = (__hip_bfloat16*)(ws + 40 * MB);
  __hip_bfloat16* xvb = (__hip_bfloat16*)(ws + 48 * MB);
  __hip_bfloat16* Wqb = (__hip_bfloat16*)(ws + 56 * MB);
  __hip_bfloat16* Wkb = (__hip_bfloat16*)(ws + 58 * MB);
  __hip_bfloat16* Wvb = (__hip_bfloat16*)(ws + 60 * MB);
  __hip_bfloat16* Wob = (__hip_bfloat16*)(ws + 62 * MB);
  unsigned long long* mbits = (unsigned long long*)(ws + 64 * MB);

  cvt_kernel<<<dim3(2048, 7), 256, 0, stream>>>(q, k, v, Wq, Wk, Wv, Wo,
                                                xqb, xkb, xvb, Wqb, Wkb, Wvb, Wob);
  maskbits_kernel<<<dim3(32768), 256, 0, stream>>>(mk, mbits);
  qkv_gemm_kernel<<<dim3(256, 1, 3), 256, 0, stream>>>(xqb, xkb, xvb,
                                                       Wqb, bq, Wkb, bk, Wvb, bv,
                                                       Qb, Kb, VTb);
  attn_kernel<<<dim3(1024), 256, 0, stream>>>(Qb, Kb, VTb, mbits, Ob);
  proj_gemm_kernel<<<dim3(256), 256, 0, stream>>>(Ob, Wob, bo, out);
}